// Round 3
// baseline (168.910 us; speedup 1.0000x reference)
//
#include <hip/hip_runtime.h>

// Batched 1D linear interpolation with clamped extrapolation.
// t: [B,N] sorted fp32, v: [B,N] fp32, r: [B,M] fp32 -> out: [B,M] fp32
constexpr int B = 2048;
constexpr int N = 4096;
constexpr int M = 4096;
constexpr int K = 2048;  // buckets; lut kept at K ints so LDS = 40960 B -> 4 blocks/CU

__global__ __launch_bounds__(256) void interp_kernel(
    const float* __restrict__ t,
    const float* __restrict__ v,
    const float* __restrict__ r,
    float* __restrict__ out) {
    __shared__ float2 stv[N];   // interleaved (t, v): final fetch is one b64 per point
    __shared__ int lut[K];      // lut[k] = first j with (int)(t[j]*K) >= k; else N

    const int b = blockIdx.x;
    const float* tb = t + (size_t)b * N;
    const float* vb = v + (size_t)b * N;
    const float* rb = r + (size_t)b * M;
    float* ob = out + (size_t)b * M;

    // Stage interleaved (t,v) with coalesced float4 global loads; init lut.
    for (int i = threadIdx.x; i < N / 4; i += blockDim.x) {
        const float4 t4 = ((const float4*)tb)[i];
        const float4 v4 = ((const float4*)vb)[i];
        stv[4 * i + 0] = make_float2(t4.x, v4.x);
        stv[4 * i + 1] = make_float2(t4.y, v4.y);
        stv[4 * i + 2] = make_float2(t4.z, v4.z);
        stv[4 * i + 3] = make_float2(t4.w, v4.w);
    }
    for (int k = threadIdx.x; k < K; k += blockDim.x) lut[k] = N;
    __syncthreads();

    // Range-fill: element j claims buckets ((int)(t[j-1]*K), (int)(t[j]*K)].
    // Disjoint ranges -> no races; every k <= (int)(t[N-1]*K) written exactly once.
    for (int j = threadIdx.x; j < N; j += blockDim.x) {
        const float tj = stv[j].x;
        int khi = (int)(tj * K);
        if (khi > K - 1) khi = K - 1;
        int klo = 0;
        if (j > 0) klo = (int)(stv[j - 1].x * K) + 1;
        for (int k = klo; k <= khi; ++k) lut[k] = j;
    }
    __syncthreads();

    const float tfirst = stv[0].x;
    const float vfirst = stv[0].y;
    const float tlast = stv[N - 1].x;
    const float vlast = stv[N - 1].y;

    for (int m = threadIdx.x; m < M; m += blockDim.x) {
        const float q = rb[m];
        int k = (int)(q * K);
        k = k < 0 ? 0 : (k > K - 1 ? K - 1 : k);
        int lo = lut[k];
        const int hi = (k == K - 1) ? N : lut[k + 1];
        // lo..hi brackets searchsorted_right(q): elements < lo have t < q,
        // elements >= hi have t > q. Scan the (avg ~2-element) bucket.
        while (lo < hi && stv[lo].x <= q) ++lo;
        const int idx = lo < 1 ? 1 : (lo > N - 1 ? N - 1 : lo);
        const float2 p0 = stv[idx - 1];
        const float2 p1 = stv[idx];
        const float denom = (p1.x == p0.x) ? 1.0f : (p1.x - p0.x);
        float o = p0.y + (q - p0.x) / denom * (p1.y - p0.y);
        o = (q < tfirst) ? vfirst : o;
        o = (q > tlast) ? vlast : o;
        ob[m] = o;
    }
}

extern "C" void kernel_launch(void* const* d_in, const int* in_sizes, int n_in,
                              void* d_out, int out_size, void* d_ws, size_t ws_size,
                              hipStream_t stream) {
    const float* t = (const float*)d_in[0];
    const float* v = (const float*)d_in[1];
    const float* r = (const float*)d_in[2];
    float* out = (float*)d_out;
    interp_kernel<<<B, 256, 0, stream>>>(t, v, r, out);
}

// Round 4
// 151.524 us; speedup vs baseline: 1.1147x; 1.1147x over previous
//
#include <hip/hip_runtime.h>

// Batched 1D linear interpolation with clamped extrapolation.
// t: [B,N] sorted fp32, v: [B,N] fp32, r: [B,M] fp32 -> out: [B,M] fp32
constexpr int B = 2048;
constexpr int N = 4096;
constexpr int M = 4096;
constexpr int K = 2048;  // buckets; LDS = 32 KB stv + 8 KB lut = 40960 B -> 4 blocks/CU

__global__ __launch_bounds__(256) void interp_kernel(
    const float* __restrict__ t,
    const float* __restrict__ v,
    const float* __restrict__ r,
    float* __restrict__ out) {
    __shared__ float2 stv[N];   // interleaved (t, v): final fetch is one b64 per point
    __shared__ int lut[K];      // lut[k] = first j with (int)(t[j]*K) >= k; else N

    const int b = blockIdx.x;
    const float* tb = t + (size_t)b * N;
    const float* vb = v + (size_t)b * N;
    const float* rb = r + (size_t)b * M;
    float* ob = out + (size_t)b * M;

    // Stage interleaved (t,v) with coalesced float4 global loads; init lut.
    for (int i = threadIdx.x; i < N / 4; i += blockDim.x) {
        const float4 t4 = ((const float4*)tb)[i];
        const float4 v4 = ((const float4*)vb)[i];
        stv[4 * i + 0] = make_float2(t4.x, v4.x);
        stv[4 * i + 1] = make_float2(t4.y, v4.y);
        stv[4 * i + 2] = make_float2(t4.z, v4.z);
        stv[4 * i + 3] = make_float2(t4.w, v4.w);
    }
    for (int k = threadIdx.x; k < K; k += blockDim.x) lut[k] = N;
    __syncthreads();

    // Range-fill: element j claims buckets ((int)(t[j-1]*K), (int)(t[j]*K)].
    // Disjoint ranges -> no races; every covered k written exactly once.
    for (int j = threadIdx.x; j < N; j += blockDim.x) {
        const float tj = stv[j].x;
        int khi = (int)(tj * K);
        if (khi > K - 1) khi = K - 1;
        int klo = 0;
        if (j > 0) klo = (int)(stv[j - 1].x * K) + 1;
        for (int k = klo; k <= khi; ++k) lut[k] = j;
    }
    __syncthreads();

    const float tfirst = stv[0].x;
    const float vfirst = stv[0].y;
    const float tlast = stv[N - 1].x;
    const float vlast = stv[N - 1].y;

    // Query loop: 8 queries/thread/iteration in phased SoA form for MLP/ILP.
    // M/4 = 1024 float4s; 256 threads x 2 float4s x 2 iterations.
    const float4* r4 = (const float4*)rb;
    float4* o4 = (float4*)ob;
    for (int base = 0; base < M / 4; base += 2 * 256) {
        const int ia = base + threadIdx.x;
        const int ib = ia + 256;
        const float4 qa = r4[ia];
        const float4 qb = r4[ib];
        float q[8] = {qa.x, qa.y, qa.z, qa.w, qb.x, qb.y, qb.z, qb.w};
        int lo[8], hi[8];

        // Phase 1: all 8 lut loads issued together.
        #pragma unroll
        for (int j = 0; j < 8; ++j) {
            int k = (int)(q[j] * K);
            k = k < 0 ? 0 : (k > K - 1 ? K - 1 : k);
            lo[j] = lut[k];
            hi[j] = (k == K - 1) ? N : lut[k + 1];
        }
        // Phase 2: branchless scan, 3 predicated steps + rare fallback.
        #pragma unroll
        for (int j = 0; j < 8; ++j) {
            #pragma unroll
            for (int s = 0; s < 3; ++s) {
                const int safe = lo[j] < N - 1 ? lo[j] : N - 1;
                const bool adv = (lo[j] < hi[j]) && (stv[safe].x <= q[j]);
                lo[j] += adv ? 1 : 0;
            }
            while (lo[j] < hi[j] && stv[lo[j]].x <= q[j]) ++lo[j];
        }
        // Phase 3: final fetches + interp math.
        float o[8];
        #pragma unroll
        for (int j = 0; j < 8; ++j) {
            const int idx = lo[j] < 1 ? 1 : (lo[j] > N - 1 ? N - 1 : lo[j]);
            const float2 p0 = stv[idx - 1];
            const float2 p1 = stv[idx];
            const float denom = (p1.x == p0.x) ? 1.0f : (p1.x - p0.x);
            float oo = p0.y + (q[j] - p0.x) / denom * (p1.y - p0.y);
            oo = (q[j] < tfirst) ? vfirst : oo;
            oo = (q[j] > tlast) ? vlast : oo;
            o[j] = oo;
        }
        o4[ia] = make_float4(o[0], o[1], o[2], o[3]);
        o4[ib] = make_float4(o[4], o[5], o[6], o[7]);
    }
}

extern "C" void kernel_launch(void* const* d_in, const int* in_sizes, int n_in,
                              void* d_out, int out_size, void* d_ws, size_t ws_size,
                              hipStream_t stream) {
    const float* t = (const float*)d_in[0];
    const float* v = (const float*)d_in[1];
    const float* r = (const float*)d_in[2];
    float* out = (float*)d_out;
    interp_kernel<<<B, 256, 0, stream>>>(t, v, r, out);
}